// Round 1
// baseline (140.915 us; speedup 1.0000x reference)
//
#include <hip/hip_runtime.h>

// Problem constants (fixed by the reference's setup_inputs):
//   N = 100000 particles, D = 100 grid cells/dim, filter_size = 5 (radius 2).
// One particle per cell guaranteed (rng.choice replace=False).
static const int DG = 100;
static const int NCELL = DG * DG * DG;   // 1e6 cells -> 4 MB int32 grid in d_ws

// Kernel 1: scatter particle index into dense cell grid.
__global__ __launch_bounds__(256) void scatter_kernel(
    const float* __restrict__ x, const float* __restrict__ y, const float* __restrict__ z,
    const float* __restrict__ dptr, int* __restrict__ cell_idx, int n)
{
    int i = blockIdx.x * blockDim.x + threadIdx.x;
    if (i >= n) return;
    float inv_d = 1.0f / dptr[0];
    // |jitter| <= 0.3*d, so roundf == jnp.round here (never near the .5 boundary)
    int cx = (int)roundf(x[i] * inv_d);
    int cy = (int)roundf(y[i] * inv_d);
    int cz = (int)roundf(z[i] * inv_d);
    cell_idx[(cz * DG + cy) * DG + cx] = i;
}

// Kernel 2: one wave (64 lanes) per particle; lanes cover the 125 stencil
// offsets in 2 passes, butterfly-reduce 6 accumulators, lane 0 writes.
__global__ __launch_bounds__(256) void force_kernel(
    const float* __restrict__ x, const float* __restrict__ y, const float* __restrict__ z,
    const float* __restrict__ vx, const float* __restrict__ vy, const float* __restrict__ vz,
    const float* __restrict__ dptr, const float* __restrict__ knptr,
    const float* __restrict__ etaptr,
    const int* __restrict__ cell_idx, float* __restrict__ out, int n)
{
    int wid  = blockIdx.x * (blockDim.x >> 6) + (threadIdx.x >> 6);
    if (wid >= n) return;           // wave-uniform exit
    int lane = threadIdx.x & 63;
    int p = wid;

    float d    = dptr[0];
    float kn   = knptr[0];
    float eta  = etaptr[0];
    float inv_d = 1.0f / d;
    float two_d = 2.0f * d;

    float px = x[p], py = y[p], pz = z[p];
    float pvx = vx[p], pvy = vy[p], pvz = vz[p];
    int cx = (int)roundf(px * inv_d);
    int cy = (int)roundf(py * inv_d);
    int cz = (int)roundf(pz * inv_d);

    float fxc = 0.f, fyc = 0.f, fzc = 0.f;
    float fxd = 0.f, fyd = 0.f, fzd = 0.f;

    #pragma unroll
    for (int t = 0; t < 2; ++t) {
        int k = lane + t * 64;
        if (k < 125) {
            int sz  = k / 25;
            int rem = k - sz * 25;
            int sy  = rem / 5;
            int sx  = rem - sy * 5;
            // reference: neighbor cell = (c - s) mod D, s in [-2,2]
            int nz = cz - (sz - 2); if (nz < 0) nz += DG; else if (nz >= DG) nz -= DG;
            int ny = cy - (sy - 2); if (ny < 0) ny += DG; else if (ny >= DG) ny -= DG;
            int nx = cx - (sx - 2); if (nx < 0) nx += DG; else if (nx >= DG) nx -= DG;
            int B = cell_idx[(nz * DG + ny) * DG + nx];
            if (B >= 0 && B != p) {
                float dxp = px - x[B];
                float dyp = py - y[B];
                float dzp = pz - z[B];
                float dist = sqrtf(dxp * dxp + dyp * dyp + dzp * dzp);
                if (dist < two_d) {
                    float denom   = fmaxf(1e-4f, dist);
                    float inv_den = 1.0f / denom;
                    float coef = kn * (dist - two_d) * inv_den;
                    fxc += coef * dxp; fyc += coef * dyp; fzc += coef * dzp;
                    float dvxp = pvx - vx[B];
                    float dvyp = pvy - vy[B];
                    float dvzp = pvz - vz[B];
                    float vn    = (dvxp * dxp + dvyp * dyp + dvzp * dzp) * inv_den;
                    float dcoef = eta * vn * inv_den;
                    fxd += dcoef * dxp; fyd += dcoef * dyp; fzd += dcoef * dzp;
                }
            }
        }
    }

    // 64-lane butterfly reduction of the 6 accumulators
    #pragma unroll
    for (int off = 32; off >= 1; off >>= 1) {
        fxc += __shfl_xor(fxc, off, 64);
        fyc += __shfl_xor(fyc, off, 64);
        fzc += __shfl_xor(fzc, off, 64);
        fxd += __shfl_xor(fxd, off, 64);
        fyd += __shfl_xor(fyd, off, 64);
        fzd += __shfl_xor(fzd, off, 64);
    }

    if (lane == 0) {
        out[p]         = fxc;
        out[n + p]     = fyc;
        out[2 * n + p] = fzc;
        out[3 * n + p] = fxd;
        out[4 * n + p] = fyd;
        out[5 * n + p] = fzd;
    }
}

extern "C" void kernel_launch(void* const* d_in, const int* in_sizes, int n_in,
                              void* d_out, int out_size, void* d_ws, size_t ws_size,
                              hipStream_t stream)
{
    const float* x     = (const float*)d_in[0];
    const float* y     = (const float*)d_in[1];
    const float* z     = (const float*)d_in[2];
    const float* vx    = (const float*)d_in[3];
    const float* vy    = (const float*)d_in[4];
    const float* vz    = (const float*)d_in[5];
    const float* dptr  = (const float*)d_in[6];
    const float* knptr = (const float*)d_in[7];
    const float* etap  = (const float*)d_in[8];
    // d_in[9] friction, d_in[10] dt: unused by the reference output.
    int n = in_sizes[0];

    int* cell_idx = (int*)d_ws;   // 4 MB grid; 0xFF bytes -> every cell = -1
    hipMemsetAsync(cell_idx, 0xFF, (size_t)NCELL * sizeof(int), stream);

    int sblocks = (n + 255) / 256;
    scatter_kernel<<<sblocks, 256, 0, stream>>>(x, y, z, dptr, cell_idx, n);

    const int waves_per_block = 4;                       // 256 threads
    int fblocks = (n + waves_per_block - 1) / waves_per_block;
    force_kernel<<<fblocks, 256, 0, stream>>>(x, y, z, vx, vy, vz,
                                              dptr, knptr, etap,
                                              cell_idx, (float*)d_out, n);
}

// Round 2
// 136.229 us; speedup vs baseline: 1.0344x; 1.0344x over previous
//
#include <hip/hip_runtime.h>

// Problem constants (fixed by the reference's setup_inputs):
//   N = 100000 particles, D = 100 grid cells/dim, filter_size = 5 (radius 2).
// One particle per cell guaranteed (rng.choice replace=False).
static const int DG = 100;
static const int PGD = DG + 4;              // halo-padded dim: 104
static const int PPLANE = PGD * PGD;        // 10816
static const int PCELLS = PGD * PGD * PGD;  // 1124864 cells -> 4.5 MB int32

// Wrap note: reference wraps neighbor indices mod 100 (torch.roll semantics),
// but wrapped pairs are >= 4.9 apart while contact needs dist < 0.1, so they
// contribute exactly 0. A -1 halo reproduces that with zero index arithmetic.

// Kernel 1: scatter particle index into padded dense cell grid.
__global__ __launch_bounds__(256) void scatter_kernel(
    const float* __restrict__ x, const float* __restrict__ y, const float* __restrict__ z,
    const float* __restrict__ dptr, int* __restrict__ cell_idx, int n)
{
    int i = blockIdx.x * blockDim.x + threadIdx.x;
    if (i >= n) return;
    float inv_d = 1.0f / dptr[0];
    // |jitter| <= 0.3*d, so roundf == jnp.round here (never near the .5 boundary)
    int cx = (int)roundf(x[i] * inv_d);
    int cy = (int)roundf(y[i] * inv_d);
    int cz = (int)roundf(z[i] * inv_d);
    cell_idx[((cz + 2) * PGD + (cy + 2)) * PGD + (cx + 2)] = i;
}

// Kernel 2: one wave (64 lanes) per particle; lanes cover the 125 stencil
// offsets in 2 passes, butterfly-reduce 6 accumulators.
__global__ __launch_bounds__(256) void force_kernel(
    const float* __restrict__ x, const float* __restrict__ y, const float* __restrict__ z,
    const float* __restrict__ vx, const float* __restrict__ vy, const float* __restrict__ vz,
    const float* __restrict__ dptr, const float* __restrict__ knptr,
    const float* __restrict__ etaptr,
    const int* __restrict__ cell_idx, float* __restrict__ out, int n)
{
    int wid  = blockIdx.x * (blockDim.x >> 6) + (threadIdx.x >> 6);
    if (wid >= n) return;           // wave-uniform exit
    int lane = threadIdx.x & 63;
    // Wave-uniform particle id -> SGPR, so particle loads go scalar and the
    // grid base lands in an SGPR pair (probe = sgpr base + const voffset).
    int p = __builtin_amdgcn_readfirstlane(wid);

    float d    = dptr[0];
    float kn   = knptr[0];
    float eta  = etaptr[0];
    float inv_d = 1.0f / d;
    float two_d = 2.0f * d;

    float px = x[p], py = y[p], pz = z[p];
    float pvx = vx[p], pvy = vy[p], pvz = vz[p];
    int cx = (int)roundf(px * inv_d);
    int cy = (int)roundf(py * inv_d);
    int cz = (int)roundf(pz * inv_d);
    int base = ((cz + 2) * PGD + (cy + 2)) * PGD + (cx + 2);
    base = __builtin_amdgcn_readfirstlane(base);
    const int* __restrict__ g = cell_idx + base;   // SGPR-uniform base pointer

    // Per-lane constant stencil offsets (slot k -> (sz,sy,sx) in [0,5)^3).
    int k1 = lane;
    int sz = k1 / 25; int r = k1 - sz * 25; int sy = r / 5; int sx = r - sy * 5;
    int off1 = (sz - 2) * PPLANE + (sy - 2) * PGD + (sx - 2);
    int k2 = lane + 64;
    bool has2 = (k2 < 125);
    int off2 = 0;
    if (has2) {
        sz = k2 / 25; r = k2 - sz * 25; sy = r / 5; sx = r - sy * 5;
        off2 = (sz - 2) * PPLANE + (sy - 2) * PGD + (sx - 2);
    }

    int B1 = g[off1];
    int B2 = has2 ? g[off2] : -1;

    float fxc = 0.f, fyc = 0.f, fzc = 0.f;
    float fxd = 0.f, fyd = 0.f, fzd = 0.f;

    #pragma unroll
    for (int t = 0; t < 2; ++t) {
        int B = (t == 0) ? B1 : B2;
        if (B >= 0 && B != p) {
            float dxp = px - x[B];
            float dyp = py - y[B];
            float dzp = pz - z[B];
            float d2 = dxp * dxp + dyp * dyp + dzp * dzp;
            float dist = __builtin_amdgcn_sqrtf(d2);   // v_sqrt_f32, ~1 ulp
            if (dist < two_d) {
                float denom   = fmaxf(1e-4f, dist);
                float inv_den = __builtin_amdgcn_rcpf(denom);  // v_rcp_f32
                float coef = kn * (dist - two_d) * inv_den;
                fxc += coef * dxp; fyc += coef * dyp; fzc += coef * dzp;
                float dvxp = pvx - vx[B];
                float dvyp = pvy - vy[B];
                float dvzp = pvz - vz[B];
                float vn    = (dvxp * dxp + dvyp * dyp + dvzp * dzp) * inv_den;
                float dcoef = eta * vn * inv_den;
                fxd += dcoef * dxp; fyd += dcoef * dyp; fzd += dcoef * dzp;
            }
        }
    }

    // 64-lane butterfly reduction of the 6 accumulators
    #pragma unroll
    for (int off = 32; off >= 1; off >>= 1) {
        fxc += __shfl_xor(fxc, off, 64);
        fyc += __shfl_xor(fyc, off, 64);
        fzc += __shfl_xor(fzc, off, 64);
        fxd += __shfl_xor(fxd, off, 64);
        fyd += __shfl_xor(fyd, off, 64);
        fzd += __shfl_xor(fzd, off, 64);
    }

    // All lanes hold the sums; lanes 0..5 each store one component.
    if (lane < 6) {
        float v = (lane == 0) ? fxc
                : (lane == 1) ? fyc
                : (lane == 2) ? fzc
                : (lane == 3) ? fxd
                : (lane == 4) ? fyd : fzd;
        out[lane * n + p] = v;
    }
}

extern "C" void kernel_launch(void* const* d_in, const int* in_sizes, int n_in,
                              void* d_out, int out_size, void* d_ws, size_t ws_size,
                              hipStream_t stream)
{
    const float* x     = (const float*)d_in[0];
    const float* y     = (const float*)d_in[1];
    const float* z     = (const float*)d_in[2];
    const float* vx    = (const float*)d_in[3];
    const float* vy    = (const float*)d_in[4];
    const float* vz    = (const float*)d_in[5];
    const float* dptr  = (const float*)d_in[6];
    const float* knptr = (const float*)d_in[7];
    const float* etap  = (const float*)d_in[8];
    // d_in[9] friction, d_in[10] dt: unused by the reference output.
    int n = in_sizes[0];

    int* cell_idx = (int*)d_ws;   // 4.5 MB padded grid; 0xFF bytes -> every cell = -1
    hipMemsetAsync(cell_idx, 0xFF, (size_t)PCELLS * sizeof(int), stream);

    int sblocks = (n + 255) / 256;
    scatter_kernel<<<sblocks, 256, 0, stream>>>(x, y, z, dptr, cell_idx, n);

    const int waves_per_block = 4;                       // 256 threads
    int fblocks = (n + waves_per_block - 1) / waves_per_block;
    force_kernel<<<fblocks, 256, 0, stream>>>(x, y, z, vx, vy, vz,
                                              dptr, knptr, etap,
                                              cell_idx, (float*)d_out, n);
}